// Round 1
// baseline (492.334 us; speedup 1.0000x reference)
//
#include <hip/hip_runtime.h>
#include <hip/hip_bf16.h>
#include <stdint.h>

#define NREL 5
#define D 64

// round-to-nearest-even fp32 -> bf16
static __device__ __forceinline__ uint16_t f2bf(float f) {
    uint32_t u = __float_as_uint(f);
    u += 0x7FFFu + ((u >> 16) & 1u);
    return (uint16_t)(u >> 16);
}

// Kernel 1: per-item transform.
//   Y[item][r][k] = sum_d W[r][d][k] * i_feat[item][d]   (bf16)
//   c[item][r]    = sum_d b[r][d]    * i_feat[item][d]   (fp32)
// Thread layout: group = gid/16 handles 4 items; lane t = gid%16 owns k-quad t.
__global__ __launch_bounds__(256) void item_transform_kernel(
    const float* __restrict__ i_feat,
    const float* __restrict__ W,
    const float* __restrict__ b,
    uint16_t* __restrict__ Y,
    float* __restrict__ cbuf,
    int nItems)
{
    const int gid = blockIdx.x * 256 + threadIdx.x;
    const int group = gid >> 4;
    const int t = gid & 15;
    const int item0 = group * 4;
    if (item0 >= nItems) return;
    const bool full = (item0 + 4 <= nItems);

    float acc[4][NREL][4];
#pragma unroll
    for (int it = 0; it < 4; ++it)
#pragma unroll
        for (int r = 0; r < NREL; ++r)
#pragma unroll
            for (int j = 0; j < 4; ++j) acc[it][r][j] = 0.f;

    for (int d4 = 0; d4 < 16; ++d4) {
        float iv[4][4];
#pragma unroll
        for (int it = 0; it < 4; ++it) {
            if (full || (item0 + it) < nItems) {
                const float4 v = *(const float4*)(i_feat + (size_t)(item0 + it) * D + d4 * 4);
                iv[it][0] = v.x; iv[it][1] = v.y; iv[it][2] = v.z; iv[it][3] = v.w;
            } else {
                iv[it][0] = 0.f; iv[it][1] = 0.f; iv[it][2] = 0.f; iv[it][3] = 0.f;
            }
        }
#pragma unroll
        for (int j = 0; j < 4; ++j) {
            const int d = d4 * 4 + j;
#pragma unroll
            for (int r = 0; r < NREL; ++r) {
                const float4 wv = *(const float4*)(W + r * (D * D) + d * D + t * 4);
#pragma unroll
                for (int it = 0; it < 4; ++it) {
                    acc[it][r][0] = fmaf(iv[it][j], wv.x, acc[it][r][0]);
                    acc[it][r][1] = fmaf(iv[it][j], wv.y, acc[it][r][1]);
                    acc[it][r][2] = fmaf(iv[it][j], wv.z, acc[it][r][2]);
                    acc[it][r][3] = fmaf(iv[it][j], wv.w, acc[it][r][3]);
                }
            }
        }
    }

    // store Y as bf16 quads
#pragma unroll
    for (int it = 0; it < 4; ++it) {
        if (!(full || (item0 + it) < nItems)) continue;
#pragma unroll
        for (int r = 0; r < NREL; ++r) {
            ushort4 o = make_ushort4(f2bf(acc[it][r][0]), f2bf(acc[it][r][1]),
                                     f2bf(acc[it][r][2]), f2bf(acc[it][r][3]));
            *(ushort4*)(Y + (size_t)(item0 + it) * (NREL * D) + r * D + t * 4) = o;
        }
    }

    // bias dots: c[item][r] = b[r] . i  (16-lane reduction; uniform within group)
#pragma unroll
    for (int it = 0; it < 4; ++it) {
        if (!(full || (item0 + it) < nItems)) continue;
        const float4 iq = *(const float4*)(i_feat + (size_t)(item0 + it) * D + t * 4);
#pragma unroll
        for (int r = 0; r < NREL; ++r) {
            const float4 bq = *(const float4*)(b + r * D + t * 4);
            float p = iq.x * bq.x + iq.y * bq.y + iq.z * bq.z + iq.w * bq.w;
            p += __shfl_xor(p, 1);
            p += __shfl_xor(p, 2);
            p += __shfl_xor(p, 4);
            p += __shfl_xor(p, 8);
            if (t == 0) cbuf[(size_t)(item0 + it) * NREL + r] = p;
        }
    }
}

// Kernel 2: per-edge gather + 5 dot-64.
// 16 lanes per edge (4 edges/wave, 16 edges/wave via 4 iterations).
__global__ __launch_bounds__(256) void edge_kernel(
    const float* __restrict__ u_feat,
    const int* __restrict__ edge_user,
    const int* __restrict__ edge_item,
    const uint16_t* __restrict__ Y,
    const float* __restrict__ cbuf,
    float* __restrict__ out,
    int nE)
{
    const int lane = threadIdx.x & 63;
    const int wave = (blockIdx.x * 256 + threadIdx.x) >> 6;
    const int sub = lane >> 4;   // edge slot within wave
    const int t = lane & 15;     // k-quad within edge

    const long e0 = (long)wave * 16 + sub;
#pragma unroll
    for (int itr = 0; itr < 4; ++itr) {
        const long e = e0 + itr * 4;
        if (e < nE) {
            const int iu = edge_user[e];
            const int ii = edge_item[e];
            const float4 uv = *(const float4*)(u_feat + (size_t)iu * D + t * 4);
            const uint16_t* yrow = Y + (size_t)ii * (NREL * D);
            float s[NREL];
#pragma unroll
            for (int r = 0; r < NREL; ++r) {
                const uint2 p = *(const uint2*)(yrow + r * D + t * 4);
                const float y0 = __uint_as_float(p.x << 16);
                const float y1 = __uint_as_float(p.x & 0xffff0000u);
                const float y2 = __uint_as_float(p.y << 16);
                const float y3 = __uint_as_float(p.y & 0xffff0000u);
                s[r] = fmaf(uv.x, y0, fmaf(uv.y, y1, fmaf(uv.z, y2, uv.w * y3)));
            }
#pragma unroll
            for (int r = 0; r < NREL; ++r) {
                s[r] += __shfl_xor(s[r], 1);
                s[r] += __shfl_xor(s[r], 2);
                s[r] += __shfl_xor(s[r], 4);
                s[r] += __shfl_xor(s[r], 8);
            }
            if (t < NREL) {
                float v = (t == 0) ? s[0] : (t == 1) ? s[1] : (t == 2) ? s[2]
                        : (t == 3) ? s[3] : s[4];
                v += cbuf[(size_t)ii * NREL + t];
                out[e * NREL + t] = v;
            }
        }
    }
}

extern "C" void kernel_launch(void* const* d_in, const int* in_sizes, int n_in,
                              void* d_out, int out_size, void* d_ws, size_t ws_size,
                              hipStream_t stream) {
    const float* u_feat    = (const float*)d_in[0];
    const float* i_feat    = (const float*)d_in[1];
    const int*   edge_user = (const int*)d_in[2];
    const int*   edge_item = (const int*)d_in[3];
    const float* W         = (const float*)d_in[4];
    const float* b         = (const float*)d_in[5];
    float* out = (float*)d_out;

    const int nItems = in_sizes[1] / D;
    const int nE = in_sizes[2];

    // workspace: Y (bf16, nItems x 5 x 64) then c (fp32, nItems x 5)
    uint16_t* Y = (uint16_t*)d_ws;
    size_t Ybytes = ((size_t)nItems * NREL * D * sizeof(uint16_t) + 255) & ~(size_t)255;
    float* cbuf = (float*)((char*)d_ws + Ybytes);

    {
        const int groups = (nItems + 3) / 4;
        const int threads = groups * 16;
        const int blocks = (threads + 255) / 256;
        item_transform_kernel<<<blocks, 256, 0, stream>>>(i_feat, W, b, Y, cbuf, nItems);
    }
    {
        const long waves = ((long)nE + 15) / 16;
        const long blocks = (waves + 3) / 4;
        edge_kernel<<<(int)blocks, 256, 0, stream>>>(u_feat, edge_user, edge_item,
                                                     Y, cbuf, out, nE);
    }
}

// Round 2
// 377.561 us; speedup vs baseline: 1.3040x; 1.3040x over previous
//
#include <hip/hip_runtime.h>
#include <hip/hip_bf16.h>
#include <stdint.h>

#define NREL 5
#define D 64
#define REC_BYTES 384   // int8 q[5][64] (320) + fp32 scale[5] (20) + fp32 c[5] (20) + pad

// round-to-nearest-even fp32 -> bf16
static __device__ __forceinline__ uint16_t f2bf(float f) {
    uint32_t u = __float_as_uint(f);
    u += 0x7FFFu + ((u >> 16) & 1u);
    return (uint16_t)(u >> 16);
}

// Kernel 0: cast u_features to bf16 (halves the per-edge u gather to one 128B line)
__global__ __launch_bounds__(256) void u_cast_kernel(
    const float* __restrict__ uf, uint16_t* __restrict__ ub, int n4)
{
    const int i = blockIdx.x * 256 + threadIdx.x;
    if (i < n4) {
        const float4 v = ((const float4*)uf)[i];
        ((ushort4*)ub)[i] = make_ushort4(f2bf(v.x), f2bf(v.y), f2bf(v.z), f2bf(v.w));
    }
}

// Kernel 1: per-item transform + int8 quantization.
//   y[r][k] = sum_d W[r][d][k] * i[d];  record: q=round(y/scale), scale=rowmax/127, c[r]=b[r].i
// group = gid/16 handles 4 items; lane t = gid%16 owns k-quad t.
__global__ __launch_bounds__(256) void item_transform_kernel(
    const float* __restrict__ i_feat,
    const float* __restrict__ W,
    const float* __restrict__ b,
    char* __restrict__ recs,
    int nItems)
{
    const int gid = blockIdx.x * 256 + threadIdx.x;
    const int group = gid >> 4;
    const int t = gid & 15;
    const int item0 = group * 4;
    if (item0 >= nItems) return;
    const bool full = (item0 + 4 <= nItems);

    float acc[4][NREL][4];
#pragma unroll
    for (int it = 0; it < 4; ++it)
#pragma unroll
        for (int r = 0; r < NREL; ++r)
#pragma unroll
            for (int j = 0; j < 4; ++j) acc[it][r][j] = 0.f;

    for (int d4 = 0; d4 < 16; ++d4) {
        float iv[4][4];
#pragma unroll
        for (int it = 0; it < 4; ++it) {
            if (full || (item0 + it) < nItems) {
                const float4 v = *(const float4*)(i_feat + (size_t)(item0 + it) * D + d4 * 4);
                iv[it][0] = v.x; iv[it][1] = v.y; iv[it][2] = v.z; iv[it][3] = v.w;
            } else {
                iv[it][0] = 0.f; iv[it][1] = 0.f; iv[it][2] = 0.f; iv[it][3] = 0.f;
            }
        }
#pragma unroll
        for (int j = 0; j < 4; ++j) {
            const int d = d4 * 4 + j;
#pragma unroll
            for (int r = 0; r < NREL; ++r) {
                const float4 wv = *(const float4*)(W + r * (D * D) + d * D + t * 4);
#pragma unroll
                for (int it = 0; it < 4; ++it) {
                    acc[it][r][0] = fmaf(iv[it][j], wv.x, acc[it][r][0]);
                    acc[it][r][1] = fmaf(iv[it][j], wv.y, acc[it][r][1]);
                    acc[it][r][2] = fmaf(iv[it][j], wv.z, acc[it][r][2]);
                    acc[it][r][3] = fmaf(iv[it][j], wv.w, acc[it][r][3]);
                }
            }
        }
    }

    // quantize + store records
#pragma unroll
    for (int it = 0; it < 4; ++it) {
        if (!(full || (item0 + it) < nItems)) continue;
        char* rec = recs + (size_t)(item0 + it) * REC_BYTES;
#pragma unroll
        for (int r = 0; r < NREL; ++r) {
            float m = fmaxf(fmaxf(fabsf(acc[it][r][0]), fabsf(acc[it][r][1])),
                            fmaxf(fabsf(acc[it][r][2]), fabsf(acc[it][r][3])));
            m = fmaxf(m, __shfl_xor(m, 1));
            m = fmaxf(m, __shfl_xor(m, 2));
            m = fmaxf(m, __shfl_xor(m, 4));
            m = fmaxf(m, __shfl_xor(m, 8));
            m = fmaxf(m, 1e-20f);
            const float qs = 127.0f / m;
            const int q0 = (int)rintf(acc[it][r][0] * qs);
            const int q1 = (int)rintf(acc[it][r][1] * qs);
            const int q2 = (int)rintf(acc[it][r][2] * qs);
            const int q3 = (int)rintf(acc[it][r][3] * qs);
            const uint32_t pw = ((uint32_t)(uint8_t)(int8_t)q0)
                              | ((uint32_t)(uint8_t)(int8_t)q1 << 8)
                              | ((uint32_t)(uint8_t)(int8_t)q2 << 16)
                              | ((uint32_t)(uint8_t)(int8_t)q3 << 24);
            *(uint32_t*)(rec + r * D + t * 4) = pw;
            if (t == 0) *(float*)(rec + NREL * D + r * 4) = m * (1.0f / 127.0f);
        }
    }

    // bias dots: c[item][r] = b[r] . i
#pragma unroll
    for (int it = 0; it < 4; ++it) {
        if (!(full || (item0 + it) < nItems)) continue;
        char* rec = recs + (size_t)(item0 + it) * REC_BYTES;
        const float4 iq = *(const float4*)(i_feat + (size_t)(item0 + it) * D + t * 4);
#pragma unroll
        for (int r = 0; r < NREL; ++r) {
            const float4 bq = *(const float4*)(b + r * D + t * 4);
            float p = iq.x * bq.x + iq.y * bq.y + iq.z * bq.z + iq.w * bq.w;
            p += __shfl_xor(p, 1);
            p += __shfl_xor(p, 2);
            p += __shfl_xor(p, 4);
            p += __shfl_xor(p, 8);
            if (t == 0) *(float*)(rec + NREL * D + NREL * 4 + r * 4) = p;
        }
    }
}

// Kernel 2: per-edge gather + 5 int8 dot-64.
// 16 lanes per edge (4 edges/wave, 16 edges/wave via 4 iterations).
__global__ __launch_bounds__(256) void edge_kernel(
    const uint16_t* __restrict__ u_bf,
    const int* __restrict__ edge_user,
    const int* __restrict__ edge_item,
    const char* __restrict__ recs,
    float* __restrict__ out,
    int nE)
{
    const int lane = threadIdx.x & 63;
    const int wave = (blockIdx.x * 256 + threadIdx.x) >> 6;
    const int sub = lane >> 4;   // edge slot within wave
    const int t = lane & 15;     // k-quad within edge

    const long e0 = (long)wave * 16 + sub;
#pragma unroll
    for (int itr = 0; itr < 4; ++itr) {
        const long e = e0 + itr * 4;
        if (e < nE) {
            const int iu = edge_user[e];
            const int ii = edge_item[e];
            // u: 4 bf16 = 8B per lane; 16 lanes cover the 128B user row
            const uint2 up = *(const uint2*)(u_bf + (size_t)iu * D + t * 4);
            const float u0 = __uint_as_float(up.x << 16);
            const float u1 = __uint_as_float(up.x & 0xffff0000u);
            const float u2 = __uint_as_float(up.y << 16);
            const float u3 = __uint_as_float(up.y & 0xffff0000u);
            const char* rec = recs + (size_t)ii * REC_BYTES;
            float s[NREL];
#pragma unroll
            for (int r = 0; r < NREL; ++r) {
                const uint32_t pq = *(const uint32_t*)(rec + r * D + t * 4);
                const float y0 = (float)((int)(pq << 24) >> 24);
                const float y1 = (float)((int)(pq << 16) >> 24);
                const float y2 = (float)((int)(pq << 8) >> 24);
                const float y3 = (float)((int)pq >> 24);
                s[r] = fmaf(u0, y0, fmaf(u1, y1, fmaf(u2, y2, u3 * y3)));
            }
#pragma unroll
            for (int r = 0; r < NREL; ++r) {
                s[r] += __shfl_xor(s[r], 1);
                s[r] += __shfl_xor(s[r], 2);
                s[r] += __shfl_xor(s[r], 4);
                s[r] += __shfl_xor(s[r], 8);
            }
            if (t < NREL) {
                const float sv = (t == 0) ? s[0] : (t == 1) ? s[1] : (t == 2) ? s[2]
                               : (t == 3) ? s[3] : s[4];
                const float scale = *(const float*)(rec + NREL * D + t * 4);
                const float c     = *(const float*)(rec + NREL * D + NREL * 4 + t * 4);
                out[e * NREL + t] = fmaf(sv, scale, c);
            }
        }
    }
}

extern "C" void kernel_launch(void* const* d_in, const int* in_sizes, int n_in,
                              void* d_out, int out_size, void* d_ws, size_t ws_size,
                              hipStream_t stream) {
    const float* u_feat    = (const float*)d_in[0];
    const float* i_feat    = (const float*)d_in[1];
    const int*   edge_user = (const int*)d_in[2];
    const int*   edge_item = (const int*)d_in[3];
    const float* W         = (const float*)d_in[4];
    const float* b         = (const float*)d_in[5];
    float* out = (float*)d_out;

    const int nUsers = in_sizes[0] / D;
    const int nItems = in_sizes[1] / D;
    const int nE = in_sizes[2];

    // workspace: item records (384B each), then u_bf16
    char* recs = (char*)d_ws;
    size_t recBytes = ((size_t)nItems * REC_BYTES + 255) & ~(size_t)255;
    uint16_t* u_bf = (uint16_t*)((char*)d_ws + recBytes);

    {
        const int n4 = nUsers * D / 4;
        u_cast_kernel<<<(n4 + 255) / 256, 256, 0, stream>>>(u_feat, u_bf, n4);
    }
    {
        const int groups = (nItems + 3) / 4;
        const int threads = groups * 16;
        const int blocks = (threads + 255) / 256;
        item_transform_kernel<<<blocks, 256, 0, stream>>>(i_feat, W, b, recs, nItems);
    }
    {
        const long waves = ((long)nE + 15) / 16;
        const long blocks = (waves + 3) / 4;
        edge_kernel<<<(int)blocks, 256, 0, stream>>>(u_bf, edge_user, edge_item,
                                                     recs, out, nE);
    }
}

// Round 3
// 358.747 us; speedup vs baseline: 1.3724x; 1.0524x over previous
//
#include <hip/hip_runtime.h>
#include <hip/hip_bf16.h>
#include <stdint.h>

#define NREL 5
#define D 64
#define REC_BYTES 384   // int8 q[5][64] (320) + fp32 scale[5] (20) + fp32 c[5] (20) + pad
#define IPW 16          // items per wave in item_transform

// round-to-nearest-even fp32 -> bf16
static __device__ __forceinline__ uint16_t f2bf(float f) {
    uint32_t u = __float_as_uint(f);
    u += 0x7FFFu + ((u >> 16) & 1u);
    return (uint16_t)(u >> 16);
}

// Kernel 0: cast u_features to bf16 (one 128B line per user row)
__global__ __launch_bounds__(256) void u_cast_kernel(
    const float* __restrict__ uf, uint16_t* __restrict__ ub, int n4)
{
    const int i = blockIdx.x * 256 + threadIdx.x;
    if (i < n4) {
        const float4 v = ((const float4*)uf)[i];
        ((ushort4*)ub)[i] = make_ushort4(f2bf(v.x), f2bf(v.y), f2bf(v.z), f2bf(v.w));
    }
}

// Kernel 1: per-item transform + int8 quantization.
// One wave per 16 items; lane k owns output column k for all relations.
//   y[it][r][k] = sum_d i[it][d] * W[r][d][k]
// W loads are coalesced dwords (256B/wave per (r,d)); i[it][d] comes from a
// register broadcast (__shfl of preloaded column), so W is read once per
// 16 items (250 MB L2 total) and all 80 accumulators stay in VGPRs.
__global__ __launch_bounds__(256) void item_transform_kernel(
    const float* __restrict__ i_feat,
    const float* __restrict__ W,
    const float* __restrict__ b,
    char* __restrict__ recs,
    int nItems)
{
    const int lane = threadIdx.x & 63;
    const int wave = (blockIdx.x * 256 + threadIdx.x) >> 6;
    const int item0 = wave * IPW;
    if (item0 >= nItems) return;

    // preload: lane holds column `lane` of each of this wave's 16 item rows
    float ireg[IPW];
#pragma unroll
    for (int it = 0; it < IPW; ++it)
        ireg[it] = (item0 + it < nItems) ? i_feat[(size_t)(item0 + it) * D + lane] : 0.f;
    float breg[NREL];
#pragma unroll
    for (int r = 0; r < NREL; ++r)
        breg[r] = b[r * D + lane];

    float acc[IPW][NREL];
#pragma unroll
    for (int it = 0; it < IPW; ++it)
#pragma unroll
        for (int r = 0; r < NREL; ++r) acc[it][r] = 0.f;

#pragma unroll 4
    for (int d = 0; d < D; ++d) {
        float wv[NREL];
#pragma unroll
        for (int r = 0; r < NREL; ++r)
            wv[r] = W[r * (D * D) + d * D + lane];
#pragma unroll
        for (int it = 0; it < IPW; ++it) {
            const float iv = __shfl(ireg[it], d);
#pragma unroll
            for (int r = 0; r < NREL; ++r)
                acc[it][r] = fmaf(iv, wv[r], acc[it][r]);
        }
    }

    // epilogue: per (it,r): wave-max -> int8 quantize -> byte store; bias dot
#pragma unroll
    for (int it = 0; it < IPW; ++it) {
        if (item0 + it >= nItems) continue;
        char* rec = recs + (size_t)(item0 + it) * REC_BYTES;
#pragma unroll
        for (int r = 0; r < NREL; ++r) {
            float m = fabsf(acc[it][r]);
            m = fmaxf(m, __shfl_xor(m, 1));
            m = fmaxf(m, __shfl_xor(m, 2));
            m = fmaxf(m, __shfl_xor(m, 4));
            m = fmaxf(m, __shfl_xor(m, 8));
            m = fmaxf(m, __shfl_xor(m, 16));
            m = fmaxf(m, __shfl_xor(m, 32));
            m = fmaxf(m, 1e-20f);
            const float qs = 127.0f / m;
            const int q = (int)rintf(acc[it][r] * qs);
            rec[r * D + lane] = (char)q;
            if (lane == 0) *(float*)(rec + NREL * D + r * 4) = m * (1.0f / 127.0f);

            float p = ireg[it] * breg[r];
            p += __shfl_xor(p, 1);
            p += __shfl_xor(p, 2);
            p += __shfl_xor(p, 4);
            p += __shfl_xor(p, 8);
            p += __shfl_xor(p, 16);
            p += __shfl_xor(p, 32);
            if (lane == 0) *(float*)(rec + NREL * D + NREL * 4 + r * 4) = p;
        }
    }
}

// Kernel 2: per-edge gather + 5 int8 dot-64.
// 16 lanes per edge (4 edges/wave, 16 edges/wave via 4 iterations).
__global__ __launch_bounds__(256) void edge_kernel(
    const uint16_t* __restrict__ u_bf,
    const int* __restrict__ edge_user,
    const int* __restrict__ edge_item,
    const char* __restrict__ recs,
    float* __restrict__ out,
    int nE)
{
    const int lane = threadIdx.x & 63;
    const int wave = (blockIdx.x * 256 + threadIdx.x) >> 6;
    const int sub = lane >> 4;   // edge slot within wave
    const int t = lane & 15;     // k-quad within edge

    const long e0 = (long)wave * 16 + sub;
#pragma unroll
    for (int itr = 0; itr < 4; ++itr) {
        const long e = e0 + itr * 4;
        if (e < nE) {
            const int iu = edge_user[e];
            const int ii = edge_item[e];
            // u: 4 bf16 = 8B per lane; 16 lanes cover the 128B user row
            const uint2 up = *(const uint2*)(u_bf + (size_t)iu * D + t * 4);
            const float u0 = __uint_as_float(up.x << 16);
            const float u1 = __uint_as_float(up.x & 0xffff0000u);
            const float u2 = __uint_as_float(up.y << 16);
            const float u3 = __uint_as_float(up.y & 0xffff0000u);
            const char* rec = recs + (size_t)ii * REC_BYTES;
            float s[NREL];
#pragma unroll
            for (int r = 0; r < NREL; ++r) {
                const uint32_t pq = *(const uint32_t*)(rec + r * D + t * 4);
                const float y0 = (float)((int)(pq << 24) >> 24);
                const float y1 = (float)((int)(pq << 16) >> 24);
                const float y2 = (float)((int)(pq << 8) >> 24);
                const float y3 = (float)((int)pq >> 24);
                s[r] = fmaf(u0, y0, fmaf(u1, y1, fmaf(u2, y2, u3 * y3)));
            }
#pragma unroll
            for (int r = 0; r < NREL; ++r) {
                s[r] += __shfl_xor(s[r], 1);
                s[r] += __shfl_xor(s[r], 2);
                s[r] += __shfl_xor(s[r], 4);
                s[r] += __shfl_xor(s[r], 8);
            }
            if (t < NREL) {
                const float sv = (t == 0) ? s[0] : (t == 1) ? s[1] : (t == 2) ? s[2]
                               : (t == 3) ? s[3] : s[4];
                const float scale = *(const float*)(rec + NREL * D + t * 4);
                const float c     = *(const float*)(rec + NREL * D + NREL * 4 + t * 4);
                out[e * NREL + t] = fmaf(sv, scale, c);
            }
        }
    }
}

extern "C" void kernel_launch(void* const* d_in, const int* in_sizes, int n_in,
                              void* d_out, int out_size, void* d_ws, size_t ws_size,
                              hipStream_t stream) {
    const float* u_feat    = (const float*)d_in[0];
    const float* i_feat    = (const float*)d_in[1];
    const int*   edge_user = (const int*)d_in[2];
    const int*   edge_item = (const int*)d_in[3];
    const float* W         = (const float*)d_in[4];
    const float* b         = (const float*)d_in[5];
    float* out = (float*)d_out;

    const int nUsers = in_sizes[0] / D;
    const int nItems = in_sizes[1] / D;
    const int nE = in_sizes[2];

    // workspace: item records (384B each), then u_bf16
    char* recs = (char*)d_ws;
    size_t recBytes = ((size_t)nItems * REC_BYTES + 255) & ~(size_t)255;
    uint16_t* u_bf = (uint16_t*)((char*)d_ws + recBytes);

    {
        const int n4 = nUsers * D / 4;
        u_cast_kernel<<<(n4 + 255) / 256, 256, 0, stream>>>(u_feat, u_bf, n4);
    }
    {
        const int waves = (nItems + IPW - 1) / IPW;
        const int blocks = (waves + 3) / 4;
        item_transform_kernel<<<blocks, 256, 0, stream>>>(i_feat, W, b, recs, nItems);
    }
    {
        const long waves = ((long)nE + 15) / 16;
        const long blocks = (waves + 3) / 4;
        edge_kernel<<<(int)blocks, 256, 0, stream>>>(u_bf, edge_user, edge_item,
                                                     recs, out, nE);
    }
}